// Round 4
// baseline (137.396 us; speedup 1.0000x reference)
//
#include <hip/hip_runtime.h>
#include <math.h>

#define Nn 100000
#define Ss 5000
#define Ee 400000
#define EPSf 1e-6f

#define NB1 391      // ceil(N/256) softmax+colsum blocks
#define NB2 20       // ceil(S/256) M blocks
#define NBP 391      // ceil(N/256) projection blocks
#define GT 20        // ceil(S/256) tiles per pdist1 axis
#define NPD1 (GT*GT) // 400 pairwise tiles
#define NB5 512      // edge-sum blocks
#define NB45 (NPD1 + NB5)

// float-offsets into workspace (16B aligned)
#define OFF_PCS  0        // colsum partials NB1*8 = 3128
#define OFF_PM   3200     // M partials NB2*64 = 1280
#define OFF_P    4608     // P (N x 2) = 200000
#define OFF_PD1  204608   // 400
#define OFF_PD2  205056   // 512
// total 205568 floats = 822 KB

__device__ __forceinline__ float block_reduce_256(float v) {
    __shared__ float red[4];
    int lane = threadIdx.x & 63, wid = threadIdx.x >> 6;
#pragma unroll
    for (int o = 32; o > 0; o >>= 1) v += __shfl_down(v, o, 64);
    if (lane == 0) red[wid] = v;
    __syncthreads();
    return (threadIdx.x == 0) ? (red[0] + red[1] + red[2] + red[3]) : 0.f;
}

__device__ __forceinline__ void softmax8(const float* __restrict__ Z, int n, float* zs) {
#pragma unroll
    for (int k = 0; k < 8; k++) zs[k] = Z[k * Nn + n];
    float m = zs[0];
#pragma unroll
    for (int k = 1; k < 8; k++) m = fmaxf(m, zs[k]);
    float s = 0.f;
#pragma unroll
    for (int k = 0; k < 8; k++) { zs[k] = __expf(zs[k] - m); s += zs[k]; }
    float inv = 1.f / s;
#pragma unroll
    for (int k = 0; k < 8; k++) zs[k] *= inv;
}

// K1: per-column softmax of Z; per-block partial colsum[k] of Zs[k,n]*sigmoid(Gate[n,k])
__global__ __launch_bounds__(256) void k1_colsum(
        const float* __restrict__ Z, const float* __restrict__ Gate,
        float* __restrict__ pcs) {
    int n = blockIdx.x * 256 + threadIdx.x;
    float p[8];
#pragma unroll
    for (int k = 0; k < 8; k++) p[k] = 0.f;
    if (n < Nn) {
        float zs[8];
        softmax8(Z, n, zs);
        float4 g0 = *(const float4*)(Gate + (long)n * 8);
        float4 g1 = *(const float4*)(Gate + (long)n * 8 + 4);
        float g[8] = {g0.x, g0.y, g0.z, g0.w, g1.x, g1.y, g1.z, g1.w};
#pragma unroll
        for (int k = 0; k < 8; k++)
            p[k] = zs[k] / (1.f + __expf(-g[k]));
    }
#pragma unroll
    for (int k = 0; k < 8; k++) {
#pragma unroll
        for (int o = 32; o > 0; o >>= 1) p[k] += __shfl_down(p[k], o, 64);
    }
    __shared__ float lds[4 * 8];
    int lane = threadIdx.x & 63, wid = threadIdx.x >> 6;
    if (lane == 0) {
#pragma unroll
        for (int k = 0; k < 8; k++) lds[wid * 8 + k] = p[k];
    }
    __syncthreads();
    if (threadIdx.x < 8) {
        float s = lds[threadIdx.x] + lds[8 + threadIdx.x] + lds[16 + threadIdx.x] + lds[24 + threadIdx.x];
        pcs[blockIdx.x * 8 + threadIdx.x] = s;
    }
}

// K2: prologue reduces pcs -> ics (per block, redundant); then per-block partial of
// M[a][b] = sum_s zs[a] * (zs[b]*sig(g[b])*ics[b])
__global__ __launch_bounds__(256) void k2_M(
        const float* __restrict__ Z, const float* __restrict__ Gate,
        const int* __restrict__ sidx, const float* __restrict__ pcs,
        float* __restrict__ pM) {
    __shared__ float ics[8];
    int t = threadIdx.x;
    if (t < 64) {
        int k = t & 7, c = t >> 3;  // 8 chunks of the b-range
        float s = 0.f;
        for (int b = c; b < NB1; b += 8) s += pcs[b * 8 + k];
        s += __shfl_xor(s, 8, 64);
        s += __shfl_xor(s, 16, 64);
        s += __shfl_xor(s, 32, 64);
        if (t < 8) ics[t] = 1.f / s;
    }
    __syncthreads();

    int s_id = blockIdx.x * 256 + t;
    float acc[64];
#pragma unroll
    for (int e = 0; e < 64; e++) acc[e] = 0.f;
    if (s_id < Ss) {
        int i = sidx[s_id];
        float zs[8];
        softmax8(Z, i, zs);
        float4 g0 = *(const float4*)(Gate + (long)i * 8);
        float4 g1 = *(const float4*)(Gate + (long)i * 8 + 4);
        float g[8] = {g0.x, g0.y, g0.z, g0.w, g1.x, g1.y, g1.z, g1.w};
        float c[8];
#pragma unroll
        for (int k = 0; k < 8; k++)
            c[k] = zs[k] * ics[k] / (1.f + __expf(-g[k]));
#pragma unroll
        for (int a = 0; a < 8; a++)
#pragma unroll
            for (int b = 0; b < 8; b++) acc[a * 8 + b] = zs[a] * c[b];
    }
#pragma unroll
    for (int e = 0; e < 64; e++) {
#pragma unroll
        for (int o = 32; o > 0; o >>= 1) acc[e] += __shfl_down(acc[e], o, 64);
    }
    __shared__ float lds[4 * 64];
    int lane = t & 63, wid = t >> 6;
    if (lane == 0) {
#pragma unroll
        for (int e = 0; e < 64; e++) lds[wid * 64 + e] = acc[e];
    }
    __syncthreads();
    if (t < 64)
        pM[blockIdx.x * 64 + t] = lds[t] + lds[64 + t] + lds[128 + t] + lds[192 + t];
}

// K3: prologue reduces pM -> M -> AZC (2x8, per block, redundant);
// then P[n] = AZC @ softmax(Z[:,n])
__global__ __launch_bounds__(256) void k3_project(
        const float* __restrict__ Z, const float* __restrict__ A,
        const float* __restrict__ pM, float* __restrict__ P) {
    __shared__ float M[64];
    __shared__ float azc[16];
    int t = threadIdx.x;
    if (t < 64) {
        float s = 0.f;
        for (int b = 0; b < NB2; b++) s += pM[b * 64 + t];
        M[t] = s;
    }
    __syncthreads();
    if (t < 16) {
        int d = t >> 3, k = t & 7;
        float v = 0.f;
#pragma unroll
        for (int j = 0; j < 8; j++) v += A[d * 8 + j] * M[j * 8 + k];
        azc[t] = v;
    }
    __syncthreads();

    int n = blockIdx.x * 256 + t;
    if (n >= Nn) return;
    float zs[8];
    softmax8(Z, n, zs);
    float px = 0.f, py = 0.f;
#pragma unroll
    for (int k = 0; k < 8; k++) { px += azc[k] * zs[k]; py += azc[8 + k] * zs[k]; }
    *(float2*)(P + (long)n * 2) = make_float2(px, py);
}

// K45: blocks [0, NPD1): S x S tile sum of exp(b_i + b_j - dist_ij)
//      blocks [NPD1, NB45): edge sum of beta_i + beta_j - edist
__global__ __launch_bounds__(256) void k45_pair_edge(
        const float* __restrict__ P, const float* __restrict__ beta,
        const int* __restrict__ sidx, const int* __restrict__ si,
        const int* __restrict__ sj, float* __restrict__ pd1_part,
        float* __restrict__ pd2_part) {
    int t = threadIdx.x;
    if (blockIdx.x < NPD1) {
        int bi_t = blockIdx.x % GT;   // i-tile
        int bj_t = blockIdx.x / GT;   // j-tile
        __shared__ float xs[256], ys[256], bs[256];
        int j = bj_t * 256 + t;
        if (j < Ss) {
            int jj = sidx[j];
            float2 p = *(const float2*)(P + (long)jj * 2);
            xs[t] = p.x; ys[t] = p.y; bs[t] = beta[jj];
        } else {
            xs[t] = 0.f; ys[t] = 0.f; bs[t] = -1e30f;
        }
        __syncthreads();
        int i = bi_t * 256 + t;
        float xi = 0.f, yi = 0.f, bi = -1e30f;
        if (i < Ss) {
            int ii = sidx[i];
            float2 p = *(const float2*)(P + (long)ii * 2);
            xi = p.x; yi = p.y; bi = beta[ii];
        }
        float acc = 0.f;
#pragma unroll 4
        for (int jc = 0; jc < 256; jc++) {
            float dx = xi - xs[jc] + EPSf;
            float dy = yi - ys[jc] + EPSf;
            float dist = sqrtf(dx * dx + dy * dy);
            acc += __expf(bi + bs[jc] - dist);
        }
        float v = block_reduce_256(acc);
        if (t == 0) pd1_part[blockIdx.x] = v;
    } else {
        int tid = (blockIdx.x - NPD1) * 256 + t;
        float acc = 0.f;
        for (int e = tid; e < Ee; e += NB5 * 256) {
            int i = si[e], j = sj[e];
            float2 pi = *(const float2*)(P + (long)i * 2);
            float2 pj = *(const float2*)(P + (long)j * 2);
            float dx = pi.x - pj.x + EPSf;
            float dy = pi.y - pj.y + EPSf;
            acc += beta[i] + beta[j] - sqrtf(dx * dx + dy * dy);
        }
        float v = block_reduce_256(acc);
        if (t == 0) pd2_part[blockIdx.x - NPD1] = v;
    }
}

// Final: out = pd2_sum - 0.5*e^2*(pd1_sum - trace); trace computed here directly.
__global__ __launch_bounds__(256) void kfin(
        const float* __restrict__ ws, const float* __restrict__ beta,
        const int* __restrict__ sidx, float* __restrict__ out) {
    const float* pd1 = ws + OFF_PD1;
    const float* pd2 = ws + OFF_PD2;
    int t = threadIdx.x;
    double a = 0.0, d = 0.0, p2 = 0.0;
    for (int i = t; i < NPD1; i += 256) a += (double)pd1[i];
    for (int i = t; i < NB5; i += 256) p2 += (double)pd2[i];
    for (int s = t; s < Ss; s += 256) {
        float b = beta[sidx[s]];
        d += (double)__expf(2.f * b - 1.41421356237f * EPSf);  // dist_ii = EPS*sqrt(2)
    }
    double v = p2 + 3.694528049465325 * (d - a);  // C = 0.5*e^2
#pragma unroll
    for (int o = 32; o > 0; o >>= 1) v += __shfl_down(v, o, 64);
    __shared__ double red[4];
    int lane = t & 63, wid = t >> 6;
    if (lane == 0) red[wid] = v;
    __syncthreads();
    if (t == 0) out[0] = (float)(red[0] + red[1] + red[2] + red[3]);
}

extern "C" void kernel_launch(void* const* d_in, const int* in_sizes, int n_in,
                              void* d_out, int out_size, void* d_ws, size_t ws_size,
                              hipStream_t stream) {
    const float* A    = (const float*)d_in[0];
    const float* Z    = (const float*)d_in[1];
    const float* Gate = (const float*)d_in[2];
    const float* beta = (const float*)d_in[3];
    const int* sidx   = (const int*)d_in[4];
    const int* si     = (const int*)d_in[5];
    const int* sj     = (const int*)d_in[6];
    float* ws  = (float*)d_ws;
    float* out = (float*)d_out;

    k1_colsum<<<NB1, 256, 0, stream>>>(Z, Gate, ws + OFF_PCS);
    k2_M<<<NB2, 256, 0, stream>>>(Z, Gate, sidx, ws + OFF_PCS, ws + OFF_PM);
    k3_project<<<NBP, 256, 0, stream>>>(Z, A, ws + OFF_PM, ws + OFF_P);
    k45_pair_edge<<<NB45, 256, 0, stream>>>(ws + OFF_P, beta, sidx, si, sj,
                                            ws + OFF_PD1, ws + OFF_PD2);
    kfin<<<1, 256, 0, stream>>>(ws, beta, sidx, out);
}

// Round 6
// 130.734 us; speedup vs baseline: 1.0510x; 1.0510x over previous
//
#include <hip/hip_runtime.h>
#include <math.h>

#define Nn 100000
#define Ss 5000
#define Ee 400000
#define EPSf 1e-6f

#define NB1 391      // ceil(N/256) softmax+colsum blocks
#define NB2 20       // ceil(S/256) M blocks
#define NBP 391      // ceil(N/256) projection blocks
#define GT 20        // ceil(S/256) tiles per pdist1 axis
#define NPD1 (GT*GT) // 400 pairwise tiles
#define NB5 512      // edge-sum blocks
#define NB45 (NPD1 + NB5)

// float-offsets into workspace (16B aligned)
#define OFF_PCS  0        // colsum partials NB1*8 = 3128
#define OFF_PM   3200     // M partials NB2*64 = 1280
#define OFF_P    4608     // P (N x 2) = 200000
#define OFF_PD1  204608   // 400 (trace-adjusted pairwise partials)
#define OFF_PD2  205056   // 512
// total 205568 floats = 822 KB

__device__ __forceinline__ float block_reduce_256(float v) {
    __shared__ float red[4];
    int lane = threadIdx.x & 63, wid = threadIdx.x >> 6;
#pragma unroll
    for (int o = 32; o > 0; o >>= 1) v += __shfl_down(v, o, 64);
    if (lane == 0) red[wid] = v;
    __syncthreads();
    return (threadIdx.x == 0) ? (red[0] + red[1] + red[2] + red[3]) : 0.f;
}

__device__ __forceinline__ void softmax8(const float* __restrict__ Z, int n, float* zs) {
#pragma unroll
    for (int k = 0; k < 8; k++) zs[k] = Z[k * Nn + n];
    float m = zs[0];
#pragma unroll
    for (int k = 1; k < 8; k++) m = fmaxf(m, zs[k]);
    float s = 0.f;
#pragma unroll
    for (int k = 0; k < 8; k++) { zs[k] = __expf(zs[k] - m); s += zs[k]; }
    float inv = 1.f / s;
#pragma unroll
    for (int k = 0; k < 8; k++) zs[k] *= inv;
}

// K1: per-column softmax of Z; per-block partial colsum[k] of Zs[k,n]*sigmoid(Gate[n,k])
__global__ __launch_bounds__(256) void k1_colsum(
        const float* __restrict__ Z, const float* __restrict__ Gate,
        float* __restrict__ pcs) {
    int n = blockIdx.x * 256 + threadIdx.x;
    float p[8];
#pragma unroll
    for (int k = 0; k < 8; k++) p[k] = 0.f;
    if (n < Nn) {
        float zs[8];
        softmax8(Z, n, zs);
        float4 g0 = *(const float4*)(Gate + (long)n * 8);
        float4 g1 = *(const float4*)(Gate + (long)n * 8 + 4);
        float g[8] = {g0.x, g0.y, g0.z, g0.w, g1.x, g1.y, g1.z, g1.w};
#pragma unroll
        for (int k = 0; k < 8; k++)
            p[k] = zs[k] / (1.f + __expf(-g[k]));
    }
#pragma unroll
    for (int k = 0; k < 8; k++) {
#pragma unroll
        for (int o = 32; o > 0; o >>= 1) p[k] += __shfl_down(p[k], o, 64);
    }
    __shared__ float lds[4 * 8];
    int lane = threadIdx.x & 63, wid = threadIdx.x >> 6;
    if (lane == 0) {
#pragma unroll
        for (int k = 0; k < 8; k++) lds[wid * 8 + k] = p[k];
    }
    __syncthreads();
    if (threadIdx.x < 8) {
        float s = lds[threadIdx.x] + lds[8 + threadIdx.x] + lds[16 + threadIdx.x] + lds[24 + threadIdx.x];
        pcs[blockIdx.x * 8 + threadIdx.x] = s;
    }
}

// K2: prologue reduces pcs -> ics (per block, redundant); then per-block partial of
// M[a][b] = sum_s zs[a] * (zs[b]*sig(g[b])*ics[b])
__global__ __launch_bounds__(256) void k2_M(
        const float* __restrict__ Z, const float* __restrict__ Gate,
        const int* __restrict__ sidx, const float* __restrict__ pcs,
        float* __restrict__ pM) {
    __shared__ float ics[8];
    int t = threadIdx.x;
    if (t < 64) {
        int k = t & 7, c = t >> 3;  // 8 chunks of the b-range
        float s = 0.f;
        for (int b = c; b < NB1; b += 8) s += pcs[b * 8 + k];
        s += __shfl_xor(s, 8, 64);
        s += __shfl_xor(s, 16, 64);
        s += __shfl_xor(s, 32, 64);
        if (t < 8) ics[t] = 1.f / s;
    }
    __syncthreads();

    int s_id = blockIdx.x * 256 + t;
    float acc[64];
#pragma unroll
    for (int e = 0; e < 64; e++) acc[e] = 0.f;
    if (s_id < Ss) {
        int i = sidx[s_id];
        float zs[8];
        softmax8(Z, i, zs);
        float4 g0 = *(const float4*)(Gate + (long)i * 8);
        float4 g1 = *(const float4*)(Gate + (long)i * 8 + 4);
        float g[8] = {g0.x, g0.y, g0.z, g0.w, g1.x, g1.y, g1.z, g1.w};
        float c[8];
#pragma unroll
        for (int k = 0; k < 8; k++)
            c[k] = zs[k] * ics[k] / (1.f + __expf(-g[k]));
#pragma unroll
        for (int a = 0; a < 8; a++)
#pragma unroll
            for (int b = 0; b < 8; b++) acc[a * 8 + b] = zs[a] * c[b];
    }
#pragma unroll
    for (int e = 0; e < 64; e++) {
#pragma unroll
        for (int o = 32; o > 0; o >>= 1) acc[e] += __shfl_down(acc[e], o, 64);
    }
    __shared__ float lds[4 * 64];
    int lane = t & 63, wid = t >> 6;
    if (lane == 0) {
#pragma unroll
        for (int e = 0; e < 64; e++) lds[wid * 64 + e] = acc[e];
    }
    __syncthreads();
    if (t < 64)
        pM[blockIdx.x * 64 + t] = lds[t] + lds[64 + t] + lds[128 + t] + lds[192 + t];
}

// K3: prologue reduces pM -> M -> AZC (2x8, per block, redundant);
// then P[n] = AZC @ softmax(Z[:,n])
__global__ __launch_bounds__(256) void k3_project(
        const float* __restrict__ Z, const float* __restrict__ A,
        const float* __restrict__ pM, float* __restrict__ P) {
    __shared__ float M[64];
    __shared__ float azc[16];
    int t = threadIdx.x;
    if (t < 64) {
        float s = 0.f;
        for (int b = 0; b < NB2; b++) s += pM[b * 64 + t];
        M[t] = s;
    }
    __syncthreads();
    if (t < 16) {
        int d = t >> 3, k = t & 7;
        float v = 0.f;
#pragma unroll
        for (int j = 0; j < 8; j++) v += A[d * 8 + j] * M[j * 8 + k];
        azc[t] = v;
    }
    __syncthreads();

    int n = blockIdx.x * 256 + t;
    if (n >= Nn) return;
    float zs[8];
    softmax8(Z, n, zs);
    float px = 0.f, py = 0.f;
#pragma unroll
    for (int k = 0; k < 8; k++) { px += azc[k] * zs[k]; py += azc[8 + k] * zs[k]; }
    *(float2*)(P + (long)n * 2) = make_float2(px, py);
}

// K45: blocks [0, NPD1): S x S tile sum of exp(b_i + b_j - dist_ij); diagonal
//      tiles subtract their trace terms so pd1 partials sum to (mat.sum - trace).
//      blocks [NPD1, NB45): edge sum of beta_i + beta_j - edist
__global__ __launch_bounds__(256) void k45_pair_edge(
        const float* __restrict__ P, const float* __restrict__ beta,
        const int* __restrict__ sidx, const int* __restrict__ si,
        const int* __restrict__ sj, float* __restrict__ pd1_part,
        float* __restrict__ pd2_part) {
    int t = threadIdx.x;
    if (blockIdx.x < NPD1) {
        int bi_t = blockIdx.x % GT;   // i-tile
        int bj_t = blockIdx.x / GT;   // j-tile
        __shared__ float xs[256], ys[256], bs[256];
        int j = bj_t * 256 + t;
        if (j < Ss) {
            int jj = sidx[j];
            float2 p = *(const float2*)(P + (long)jj * 2);
            xs[t] = p.x; ys[t] = p.y; bs[t] = beta[jj];
        } else {
            xs[t] = 0.f; ys[t] = 0.f; bs[t] = -1e30f;
        }
        __syncthreads();
        int i = bi_t * 256 + t;
        float xi = 0.f, yi = 0.f, bi = -1e30f;
        if (i < Ss) {
            int ii = sidx[i];
            float2 p = *(const float2*)(P + (long)ii * 2);
            xi = p.x; yi = p.y; bi = beta[ii];
        }
        float xie = xi + EPSf, yie = yi + EPSf;   // hoist +EPS out of the loop
        float acc = 0.f;
#pragma unroll 4
        for (int jc = 0; jc < 256; jc++) {
            float dx = xie - xs[jc];
            float dy = yie - ys[jc];
            float dist = sqrtf(dx * dx + dy * dy);
            acc += __expf(bi + bs[jc] - dist);
        }
        // diagonal tile: remove trace contribution here (dist_ii = EPS*sqrt(2))
        if (bi_t == bj_t && i < Ss)
            acc -= __expf(2.f * bi - 1.41421356237f * EPSf);
        float v = block_reduce_256(acc);
        if (t == 0) pd1_part[blockIdx.x] = v;
    } else {
        int tid = (blockIdx.x - NPD1) * 256 + t;
        float acc = 0.f;
        for (int e = tid; e < Ee; e += NB5 * 256) {
            int i = si[e], j = sj[e];
            float2 pi = *(const float2*)(P + (long)i * 2);
            float2 pj = *(const float2*)(P + (long)j * 2);
            float dx = pi.x - pj.x + EPSf;
            float dy = pi.y - pj.y + EPSf;
            acc += beta[i] + beta[j] - sqrtf(dx * dx + dy * dy);
        }
        float v = block_reduce_256(acc);
        if (t == 0) pd2_part[blockIdx.x - NPD1] = v;
    }
}

// Final: out = pd2_sum - 0.5*e^2 * pd1_sum   (pd1 already trace-adjusted)
__global__ __launch_bounds__(256) void kfin(
        const float* __restrict__ ws, float* __restrict__ out) {
    const float* pd1 = ws + OFF_PD1;
    const float* pd2 = ws + OFF_PD2;
    int t = threadIdx.x;
    double a = 0.0, p2 = 0.0;
    for (int i = t; i < NPD1; i += 256) a += (double)pd1[i];
    for (int i = t; i < NB5; i += 256) p2 += (double)pd2[i];
    double v = p2 - 3.694528049465325 * a;  // C = 0.5*e^2
#pragma unroll
    for (int o = 32; o > 0; o >>= 1) v += __shfl_down(v, o, 64);
    __shared__ double red[4];
    int lane = t & 63, wid = t >> 6;
    if (lane == 0) red[wid] = v;
    __syncthreads();
    if (t == 0) out[0] = (float)(red[0] + red[1] + red[2] + red[3]);
}

extern "C" void kernel_launch(void* const* d_in, const int* in_sizes, int n_in,
                              void* d_out, int out_size, void* d_ws, size_t ws_size,
                              hipStream_t stream) {
    const float* A    = (const float*)d_in[0];
    const float* Z    = (const float*)d_in[1];
    const float* Gate = (const float*)d_in[2];
    const float* beta = (const float*)d_in[3];
    const int* sidx   = (const int*)d_in[4];
    const int* si     = (const int*)d_in[5];
    const int* sj     = (const int*)d_in[6];
    float* ws  = (float*)d_ws;
    float* out = (float*)d_out;

    k1_colsum<<<NB1, 256, 0, stream>>>(Z, Gate, ws + OFF_PCS);
    k2_M<<<NB2, 256, 0, stream>>>(Z, Gate, sidx, ws + OFF_PCS, ws + OFF_PM);
    k3_project<<<NBP, 256, 0, stream>>>(Z, A, ws + OFF_PM, ws + OFF_P);
    k45_pair_edge<<<NB45, 256, 0, stream>>>(ws + OFF_P, beta, sidx, si, sj,
                                            ws + OFF_PD1, ws + OFF_PD2);
    kfin<<<1, 256, 0, stream>>>(ws, out);
}